// Round 1
// baseline (10340.211 us; speedup 1.0000x reference)
//
#include <hip/hip_runtime.h>
#include <hip/hip_bf16.h>

// Problem constants: x [N=32, C=64, H=128, W=128] fp32, 3x3 convs stride1 pad1.
#define NB   32
#define CH   64
#define HH   128
#define WW   128
#define HW   (HH*WW)            // 16384
#define CHW  (CH*HW)            // 1048576
#define NCHW (NB*CHW)           // 33554432
#define CNT_PER_CH ((float)(NB*HW))   // 524288

// ---------------------------------------------------------------------------
// finalize: sums -> fused scale/bias  (BN(y) = y*scale + bias)
__global__ void finalize_bn(const float* __restrict__ sum,
                            const float* __restrict__ sumsq,
                            const float* __restrict__ gamma,
                            const float* __restrict__ beta,
                            float* __restrict__ scale,
                            float* __restrict__ bias) {
    int c = threadIdx.x;
    if (c < CH) {
        float mean = sum[c] * (1.0f / CNT_PER_CH);
        float var  = sumsq[c] * (1.0f / CNT_PER_CH) - mean * mean;
        float inv  = rsqrtf(var + 1e-5f);
        float sc   = inv * gamma[c];
        scale[c] = sc;
        bias[c]  = beta[c] - mean * sc;
    }
}

// ---------------------------------------------------------------------------
// Direct 3x3 conv. Each block: 256 consecutive output pixels of one (n,co)
// plane (2 rows of W=128). Weights for co staged in LDS. Optionally applies a
// per-input-channel affine (fused BN1) to in-bounds loads only (padding stays
// zero, matching the reference which pads the *normalized* tensor with 0).
// Optionally adds residual. Fused per-channel sum/sumsq reduction for the
// following BN's batch statistics.
template <bool BNIN, bool RESID>
__global__ __launch_bounds__(256)
void conv3x3_k(const float* __restrict__ in, const float* __restrict__ wgt,
               float* __restrict__ out,
               const float* __restrict__ inscale, const float* __restrict__ inbias,
               const float* __restrict__ resid,
               float* __restrict__ sum, float* __restrict__ sumsq) {
    __shared__ float wl[576];
    __shared__ float sl[CH], bl[CH];
    __shared__ float r1[4], r2[4];

    const int tid   = threadIdx.x;
    const int plane = blockIdx.x >> 6;                 // n*64 + co
    const int pix   = ((blockIdx.x & 63) << 8) + tid;  // 0..16383
    const int n  = plane >> 6;
    const int co = plane & 63;
    const int h  = pix >> 7;
    const int w  = pix & 127;

    for (int i = tid; i < 576; i += 256) wl[i] = wgt[co * 576 + i];
    if (BNIN && tid < CH) { sl[tid] = inscale[tid]; bl[tid] = inbias[tid]; }
    __syncthreads();

    const float* img = in + (size_t)n * CHW;
    float acc = 0.f;
    for (int ci = 0; ci < CH; ++ci) {
        const float* p  = img + ci * HW;
        const float* wp = &wl[ci * 9];
        float s = 1.f, bz = 0.f;
        if (BNIN) { s = sl[ci]; bz = bl[ci]; }
#pragma unroll
        for (int kh = 0; kh < 3; ++kh) {
            int hh = h + kh - 1;
            if ((unsigned)hh < (unsigned)HH) {
                const float* row = p + hh * WW;
#pragma unroll
                for (int kw = 0; kw < 3; ++kw) {
                    int ww = w + kw - 1;
                    if ((unsigned)ww < (unsigned)WW) {
                        float v = row[ww];
                        if (BNIN) v = fmaf(v, s, bz);
                        acc = fmaf(v, wp[kh * 3 + kw], acc);
                    }
                }
            }
        }
    }

    size_t oidx = (size_t)plane * HW + pix;
    if (RESID) acc += resid[oidx];
    out[oidx] = acc;

    // block reduction of sum / sumsq for this channel (all 256 px same co)
    float s1 = acc, s2 = acc * acc;
#pragma unroll
    for (int off = 32; off; off >>= 1) {
        s1 += __shfl_down(s1, off);
        s2 += __shfl_down(s2, off);
    }
    int wid = tid >> 6;
    if ((tid & 63) == 0) { r1[wid] = s1; r2[wid] = s2; }
    __syncthreads();
    if (tid == 0) {
        atomicAdd(&sum[co],   r1[0] + r1[1] + r1[2] + r1[3]);
        atomicAdd(&sumsq[co], r2[0] + r2[1] + r2[2] + r2[3]);
    }
}

// ---------------------------------------------------------------------------
// In-place BN2 apply on d_out, float4-vectorized.
__global__ __launch_bounds__(256)
void apply_bn_k(float* __restrict__ out,
                const float* __restrict__ scale, const float* __restrict__ bias) {
    __shared__ float sc[CH], bs[CH];
    if (threadIdx.x < CH) { sc[threadIdx.x] = scale[threadIdx.x]; bs[threadIdx.x] = bias[threadIdx.x]; }
    __syncthreads();
    const size_t total4 = NCHW / 4;
    for (size_t i = (size_t)blockIdx.x * blockDim.x + threadIdx.x; i < total4;
         i += (size_t)gridDim.x * blockDim.x) {
        float4 v = reinterpret_cast<float4*>(out)[i];
        int c = (int)(((i * 4) >> 14) & 63);
        float s = sc[c], b = bs[c];
        v.x = fmaf(v.x, s, b);
        v.y = fmaf(v.y, s, b);
        v.z = fmaf(v.z, s, b);
        v.w = fmaf(v.w, s, b);
        reinterpret_cast<float4*>(out)[i] = v;
    }
}

// ---------------------------------------------------------------------------
extern "C" void kernel_launch(void* const* d_in, const int* in_sizes, int n_in,
                              void* d_out, int out_size, void* d_ws, size_t ws_size,
                              hipStream_t stream) {
    const float* x  = (const float*)d_in[0];
    const float* w1 = (const float*)d_in[1];
    const float* w2 = (const float*)d_in[2];
    const float* g1 = (const float*)d_in[3];
    const float* b1 = (const float*)d_in[4];
    const float* g2 = (const float*)d_in[5];
    const float* b2 = (const float*)d_in[6];
    float* out = (float*)d_out;

    // workspace layout
    float* y1    = (float*)d_ws;               // NCHW floats (134 MB)
    float* stats = y1 + NCHW;
    float* sum1   = stats;          // 64
    float* sq1    = stats + 64;     // 64
    float* sum2   = stats + 128;    // 64
    float* sq2    = stats + 192;    // 64
    float* scale1 = stats + 256;    // 64
    float* bias1  = stats + 320;    // 64
    float* scale2 = stats + 384;    // 64
    float* bias2  = stats + 448;    // 64

    // zero the accumulators (capture-safe async memset)
    hipMemsetAsync(stats, 0, 256 * sizeof(float), stream);

    const int conv_blocks = NCHW / 256;  // 131072

    // conv1: y1 = conv(x, w1); accumulate BN1 stats
    conv3x3_k<false, false><<<conv_blocks, 256, 0, stream>>>(
        x, w1, y1, nullptr, nullptr, nullptr, sum1, sq1);

    finalize_bn<<<1, 64, 0, stream>>>(sum1, sq1, g1, b1, scale1, bias1);

    // conv2: out = conv(BN1(y1), w2) + x; accumulate BN2 stats
    conv3x3_k<true, true><<<conv_blocks, 256, 0, stream>>>(
        y1, w2, out, scale1, bias1, x, sum2, sq2);

    finalize_bn<<<1, 64, 0, stream>>>(sum2, sq2, g2, b2, scale2, bias2);

    // BN2 apply in place on d_out
    apply_bn_k<<<2048, 256, 0, stream>>>(out, scale2, bias2);
}

// Round 2
// 538.224 us; speedup vs baseline: 19.2117x; 19.2117x over previous
//
#include <hip/hip_runtime.h>
#include <hip/hip_bf16.h>

// x [N=32, C=64, H=128, W=128] fp32; two 3x3 convs (stride1 pad1) + train-mode BN + residual.
#define NB 32
#define CH 64
#define HH 128
#define WW 128
#define HW (HH*WW)          // 16384
#define CHW (CH*HW)         // 1048576
#define NCHW (NB*CHW)       // 33554432
#define CNT_PER_CH ((float)(NB*HW))

typedef __attribute__((ext_vector_type(8)))  short short8;
typedef __attribute__((ext_vector_type(16))) float f32x16;

__device__ __forceinline__ unsigned short f2bf(float f) {
  unsigned u = __builtin_bit_cast(unsigned, f);
  u += 0x7fffu + ((u >> 16) & 1u);          // round-to-nearest-even
  return (unsigned short)(u >> 16);
}

__device__ __forceinline__ void gld_lds16(const void* g, void* s) {
  __builtin_amdgcn_global_load_lds(
      (const __attribute__((address_space(1))) unsigned int*)g,
      (__attribute__((address_space(3))) unsigned int*)s, 16, 0, 0);
}

// ---------------------------------------------------------------------------
// T1: x NCHW fp32 -> blocked NHWC bf16: xb[n][h][cb=ci/8][w][ci%8]
__global__ __launch_bounds__(256) void t1_pack(const float* __restrict__ x,
                                               unsigned short* __restrict__ xb) {
  __shared__ __align__(16) unsigned short tmp[CH * WW];   // [ci][w] 16KB
  const int bid = blockIdx.x;                 // n*128 + h
  const int tid = threadIdx.x;
  const float* src = x + (size_t)(bid >> 7) * CHW + (size_t)(bid & 127) * WW;
  for (int i = tid; i < 2048; i += 256) {     // 64 ci * 32 float4
    const int ci = i >> 5, wq = i & 31;
    const float4 v = *(const float4*)(src + (size_t)ci * HW + wq * 4);
    unsigned short* d = &tmp[ci * WW + wq * 4];
    d[0] = f2bf(v.x); d[1] = f2bf(v.y); d[2] = f2bf(v.z); d[3] = f2bf(v.w);
  }
  __syncthreads();
  unsigned short* dst = xb + (size_t)bid * 8192;          // 8 cb * 128 w * 8
  for (int i = tid; i < 1024; i += 256) {     // chunks (cb,w)
    const int cb = i >> 7, w = i & 127;
    const unsigned short* s = &tmp[cb * 8 * WW + w];
    uint4 o;
    o.x = (unsigned)s[0]      | ((unsigned)s[WW]     << 16);
    o.y = (unsigned)s[2*WW]   | ((unsigned)s[3*WW]   << 16);
    o.z = (unsigned)s[4*WW]   | ((unsigned)s[5*WW]   << 16);
    o.w = (unsigned)s[6*WW]   | ((unsigned)s[7*WW]   << 16);
    *(uint4*)(dst + ((size_t)cb * WW + w) * 8) = o;
  }
}

// ---------------------------------------------------------------------------
// Weight prepack into MFMA A-fragment order (M=co, K=ci per tap).
// frag f = ((kh*3+kw)*4 + kq)*2 + m ; element [f][lane][r] =
//   w[co=(lane&31)+32m][ci=kq*16+(lane>>5)*8+r][kh][kw]  (* s1[ci] if folding)
// Also emits BN1-bias border tables for conv2 (tabs[9][64]).
__global__ __launch_bounds__(256) void pack_w(const float* __restrict__ w,
                                              const float* __restrict__ s1,
                                              const float* __restrict__ b1,
                                              unsigned short* __restrict__ wpk,
                                              float* __restrict__ tabs) {
  const int tid = threadIdx.x;
  for (int idx = tid; idx < 36864; idx += 256) {
    const int f = idx >> 9, l = (idx >> 3) & 63, r = idx & 7;
    const int m = f & 1, kq = (f >> 1) & 3, t = f >> 3;   // t = kh*3+kw
    const int co = (l & 31) + 32 * m;
    const int ci = kq * 16 + (l >> 5) * 8 + r;
    float v = w[co * 576 + ci * 9 + t];
    if (s1) v *= s1[ci];
    wpk[idx] = f2bf(v);
  }
  if (tabs != nullptr && tid < 64) {
    const int co = tid;
    float tb[9];
    for (int t = 0; t < 9; ++t) {
      float a = 0.f;
      for (int ci = 0; ci < 64; ++ci) a += w[co * 576 + ci * 9 + t] * b1[ci];
      tb[t] = a;
    }
    tabs[0*64+co] = tb[0]+tb[1]+tb[2]+tb[3]+tb[4]+tb[5]+tb[6]+tb[7]+tb[8];
    tabs[1*64+co] = tb[0]+tb[1]+tb[2];   // kh=0 row
    tabs[2*64+co] = tb[6]+tb[7]+tb[8];   // kh=2 row
    tabs[3*64+co] = tb[0]+tb[3]+tb[6];   // kw=0 col
    tabs[4*64+co] = tb[2]+tb[5]+tb[8];   // kw=2 col
    tabs[5*64+co] = tb[0]; tabs[6*64+co] = tb[2];
    tabs[7*64+co] = tb[6]; tabs[8*64+co] = tb[8];
  }
}

// ---------------------------------------------------------------------------
// MFMA conv: block = one (n,h) row (128 w x 64 co), 4 waves x 32 px each.
// LDS A: [row(3)][cb(8)][slot(132)][8ci] bf16; slots 0/129 = zero w-halo.
template <bool IS2>
__global__ __launch_bounds__(256)
void conv_mfma(const unsigned short* __restrict__ inb,
               const unsigned short* __restrict__ wpack,
               const float* __restrict__ tabs,
               const float* __restrict__ resid,
               unsigned short* __restrict__ outb,
               float* __restrict__ outf,
               float* __restrict__ psum, float* __restrict__ psq) {
  __shared__ __align__(16) unsigned short A[3 * 8 * 132 * 8];   // 50688 B
  const int tid = threadIdx.x, bid = blockIdx.x;
  const int n = bid >> 7, h = bid & 127;
  const int wv = tid >> 6, lane = tid & 63;
  const int half = lane >> 5, lp = lane & 31;
  const int wb = wv * 32;

  if (tid < 48) {   // zero the two w-halo slots for each (row, cb)
    const int r = tid >> 4, cb = (tid & 15) >> 1, s = (tid & 1) ? 129 : 0;
    *(uint4*)&A[((r * 8 + cb) * 132 + s) * 8] = make_uint4(0, 0, 0, 0);
  }
  for (int q = wv; q < 48; q += 4) {   // stage in-bounds rows, 1KB per instr
    const int r = q >> 4, cb = (q & 15) >> 1, hf = q & 1;
    const int hr = h - 1 + r;
    if ((unsigned)hr < 128u) {
      const unsigned short* g =
          inb + ((((size_t)n * 128 + hr) * 8 + cb) * 128 + hf * 64) * 8 + (size_t)lane * 8;
      gld_lds16(g, &A[((r * 8 + cb) * 132 + 1 + hf * 64) * 8]);
    }
  }
  __syncthreads();

  f32x16 acc0 = {}; f32x16 acc1 = {};
  const int kh0 = (h == 0) ? 1 : 0;
  const int kh1 = (h == 127) ? 1 : 2;
  for (int kh = kh0; kh <= kh1; ++kh) {
    for (int kw = 0; kw < 3; ++kw) {
#pragma unroll
      for (int kq = 0; kq < 4; ++kq) {
        const short8 bfrag =
            *(const short8*)&A[((kh * 8 + kq * 2 + half) * 132 + (wb + lp + kw)) * 8];
        const int f = ((kh * 3 + kw) * 4 + kq) * 2;
        const short8 w0 = *(const short8*)(wpack + (size_t)f * 512 + lane * 8);
        const short8 w1 = *(const short8*)(wpack + (size_t)(f + 1) * 512 + lane * 8);
        acc0 = __builtin_amdgcn_mfma_f32_32x32x16_bf16(w0, bfrag, acc0, 0, 0, 0);
        acc1 = __builtin_amdgcn_mfma_f32_32x32x16_bf16(w1, bfrag, acc1, 0, 0, 0);
      }
    }
  }

  if (!IS2) {
    // pack bf16, blocked-NHWC store (fills every 16B slot across the 2 lane halves)
    unsigned short* dst = outb + (size_t)bid * 8192;
#pragma unroll
    for (int m = 0; m < 2; ++m) {
      const f32x16& a = m ? acc1 : acc0;
#pragma unroll
      for (int q = 0; q < 4; ++q) {
        uint2 pk;
        pk.x = (unsigned)f2bf(a[q*4+0]) | ((unsigned)f2bf(a[q*4+1]) << 16);
        pk.y = (unsigned)f2bf(a[q*4+2]) | ((unsigned)f2bf(a[q*4+3]) << 16);
        *(uint2*)(dst + ((size_t)(q + 4*m) * 128 + wb + lp) * 8 + half * 4) = pk;
      }
    }
  } else {
    const int w = wb + lp;
    const bool bh0 = (h == 0), bh1 = (h == 127);
    const bool bw0 = (w == 0), bw1 = (w == 127);
#pragma unroll
    for (int m = 0; m < 2; ++m) {
      f32x16& a = m ? acc1 : acc0;
#pragma unroll
      for (int q = 0; q < 4; ++q) {
#pragma unroll
        for (int j = 0; j < 4; ++j) {
          const int co = j + 8*q + 4*half + 32*m;
          float v = a[q*4+j];
          float tb = tabs[co];                       // full BN1-bias term
          if (bh0) tb -= tabs[64 + co];
          if (bh1) tb -= tabs[128 + co];
          if (bw0) tb -= tabs[192 + co];
          if (bw1) tb -= tabs[256 + co];
          if (bh0 && bw0) tb += tabs[320 + co];
          if (bh0 && bw1) tb += tabs[384 + co];
          if (bh1 && bw0) tb += tabs[448 + co];
          if (bh1 && bw1) tb += tabs[512 + co];
          v += tb;
          const size_t oi = (((size_t)n * 64 + co) * HW) + (size_t)h * WW + w;
          v += resid[oi];
          outf[oi] = v;
          a[q*4+j] = v;                              // keep for stats
        }
      }
    }
  }

  // ---- per-channel batch stats via LDS transpose (reuse A) ----
  __syncthreads();
  float* sf = (float*)A;                             // [co][128] f32, 32KB
#pragma unroll
  for (int m = 0; m < 2; ++m) {
    const f32x16& a = m ? acc1 : acc0;
#pragma unroll
    for (int q = 0; q < 4; ++q)
#pragma unroll
      for (int j = 0; j < 4; ++j)
        sf[(j + 8*q + 4*half + 32*m) * 128 + wb + lp] = a[q*4+j];
  }
  __syncthreads();
  {
    const int co = tid >> 2, qt = tid & 3;
    const float* p = &sf[co * 128 + qt * 32];
    float s = 0.f, q2 = 0.f;
#pragma unroll
    for (int i = 0; i < 32; i += 4) {
      const float4 v = *(const float4*)&p[i];
      s  += v.x + v.y + v.z + v.w;
      q2 += v.x*v.x + v.y*v.y + v.z*v.z + v.w*v.w;
    }
    s  += __shfl_xor(s, 1);  s  += __shfl_xor(s, 2);
    q2 += __shfl_xor(q2, 1); q2 += __shfl_xor(q2, 2);
    if (qt == 0) {
      atomicAdd(&psum[(bid & 63) * 64 + co], s);
      atomicAdd(&psq [(bid & 63) * 64 + co], q2);
    }
  }
}

// ---------------------------------------------------------------------------
__global__ void finalize_bn(const float* __restrict__ psum, const float* __restrict__ psq,
                            const float* __restrict__ gamma, const float* __restrict__ beta,
                            float* __restrict__ scale, float* __restrict__ bias) {
  const int c = threadIdx.x;
  if (c < 64) {
    float s = 0.f, q = 0.f;
    for (int i = 0; i < 64; ++i) { s += psum[i * 64 + c]; q += psq[i * 64 + c]; }
    const float mean = s * (1.0f / CNT_PER_CH);
    const float var  = q * (1.0f / CNT_PER_CH) - mean * mean;
    const float inv  = rsqrtf(var + 1e-5f);
    const float sc   = inv * gamma[c];
    scale[c] = sc;
    bias[c]  = beta[c] - mean * sc;
  }
}

// In-place BN2 apply on d_out, float4-vectorized.
__global__ __launch_bounds__(256)
void apply_bn_k(float* __restrict__ out,
                const float* __restrict__ scale, const float* __restrict__ bias) {
  __shared__ float sc[CH], bs[CH];
  if (threadIdx.x < CH) { sc[threadIdx.x] = scale[threadIdx.x]; bs[threadIdx.x] = bias[threadIdx.x]; }
  __syncthreads();
  const size_t total4 = NCHW / 4;
  for (size_t i = (size_t)blockIdx.x * blockDim.x + threadIdx.x; i < total4;
       i += (size_t)gridDim.x * blockDim.x) {
    float4 v = reinterpret_cast<float4*>(out)[i];
    const int c = (int)(((i * 4) >> 14) & 63);
    const float s = sc[c], b = bs[c];
    v.x = fmaf(v.x, s, b);
    v.y = fmaf(v.y, s, b);
    v.z = fmaf(v.z, s, b);
    v.w = fmaf(v.w, s, b);
    reinterpret_cast<float4*>(out)[i] = v;
  }
}

// ---------------------------------------------------------------------------
extern "C" void kernel_launch(void* const* d_in, const int* in_sizes, int n_in,
                              void* d_out, int out_size, void* d_ws, size_t ws_size,
                              hipStream_t stream) {
  const float* x  = (const float*)d_in[0];
  const float* w1 = (const float*)d_in[1];
  const float* w2 = (const float*)d_in[2];
  const float* g1 = (const float*)d_in[3];
  const float* b1 = (const float*)d_in[4];
  const float* g2 = (const float*)d_in[5];
  const float* b2 = (const float*)d_in[6];
  float* out = (float*)d_out;
  char* ws = (char*)d_ws;

  // ws: [XB bf16 64MiB][Y1B bf16 64MiB] == exactly 128 MiB (proven available)
  unsigned short* XB  = (unsigned short*)ws;
  unsigned short* Y1B = (unsigned short*)(ws + 67108864);
  // overlays in XB region (XB dead after conv1):
  unsigned short* W2P = (unsigned short*)ws;          // 73728 B
  float* TABS = (float*)(ws + 73728);                 // 2304 B
  float* SC1  = (float*)(ws + 76032);
  float* BS1  = (float*)(ws + 76288);
  float* SC2  = (float*)(ws + 76544);
  float* BS2  = (float*)(ws + 76800);
  float* P2S  = (float*)(ws + 77056);                 // 16 KB
  float* P2Q  = (float*)(ws + 93440);                 // 16 KB
  // overlays in d_out (free until conv2 writes it):
  char* ob = (char*)d_out;
  unsigned short* W1P = (unsigned short*)ob;          // 73728 B
  float* P1S = (float*)(ob + 73728);                  // 16 KB
  float* P1Q = (float*)(ob + 90112);                  // 16 KB

  hipMemsetAsync(ob + 73728, 0, 32768, stream);                    // zero P1
  pack_w<<<1, 256, 0, stream>>>(w1, nullptr, nullptr, W1P, nullptr);
  t1_pack<<<4096, 256, 0, stream>>>(x, XB);
  conv_mfma<false><<<4096, 256, 0, stream>>>(XB, W1P, nullptr, nullptr,
                                             Y1B, nullptr, P1S, P1Q);
  finalize_bn<<<1, 64, 0, stream>>>(P1S, P1Q, g1, b1, SC1, BS1);
  hipMemsetAsync(ws + 77056, 0, 32768, stream);                    // zero P2 (XB dead)
  pack_w<<<1, 256, 0, stream>>>(w2, SC1, BS1, W2P, TABS);
  conv_mfma<true><<<4096, 256, 0, stream>>>(Y1B, W2P, TABS, x,
                                            nullptr, out, P2S, P2Q);
  finalize_bn<<<1, 64, 0, stream>>>(P2S, P2Q, g2, b2, SC2, BS2);
  apply_bn_k<<<2048, 256, 0, stream>>>(out, SC2, BS2);
}